// Round 1
// baseline (168.407 us; speedup 1.0000x reference)
//
#include <hip/hip_runtime.h>
#include <cstdint>
#include <cstddef>

// Problem: B=8,S=2048,E=512,FFN=2048,Q=8  ->  M=16384, K=2048, N=512.
// Fused design: act (z@w1^T+b1, relu, bf16) is computed IN the GEMM kernel
// per K-step (K=8 inner dim => 1.6% of GEMM2 FLOPs), eliminating the 64 MB
// act write + 64 MB read and the whole k_act kernel.

typedef __attribute__((ext_vector_type(8))) short s16x8;
typedef __attribute__((ext_vector_type(4))) float f32x4;

// round-to-nearest-even fp32 -> bf16
__device__ __forceinline__ unsigned short f2bf(float f) {
  unsigned int u = __float_as_uint(f);
  unsigned int r = u + 0x7fffu + ((u >> 16) & 1u);
  return (unsigned short)(r >> 16);
}

__device__ __forceinline__ void async_copy16(const void* g, void* l) {
  __builtin_amdgcn_global_load_lds(
      (const __attribute__((address_space(1))) void*)(uintptr_t)g,
      (__attribute__((address_space(3))) void*)(unsigned int)(uintptr_t)l,
      16, 0, 0);
}

// ---------------------------------------------------------------------------
// Kernel 1: w2 (fp32 [512][2048]) -> bf16 same layout (one-time, ~2 us)
// ---------------------------------------------------------------------------
__global__ __launch_bounds__(256) void k_w2(const float* __restrict__ w2,
                                            unsigned short* __restrict__ w2b) {
  size_t i = ((size_t)blockIdx.x * 256 + threadIdx.x) * 4;
  float4 v = *(const float4*)(w2 + i);
  uint2 p;
  p.x = f2bf(v.x) | ((unsigned)f2bf(v.y) << 16);
  p.y = f2bf(v.z) | ((unsigned)f2bf(v.w) << 16);
  *(uint2*)(w2b + i) = p;
}

// ---------------------------------------------------------------------------
// Kernel 2 (fused): C[m][n] = sum_k relu(z[m]·w1[k]+b1[k]) * w2b[n][k] + b2[n]
// grid = 256 blocks (128 mt x 2 nt) = exactly 1 block/CU.
// 512 threads = 8 waves; wave w owns 64x64 tile at (wm=(w>>2)*64, wn=(w&3)*64).
// Per K-step (32 k):
//   A: issue async Bs stage (w2b slice) + w1 reg-prefetch for kt+1
//   B: VALU act-compute -> ds_write As  (fills the staging-latency stall)
//   sync ; C: 16 MFMA/wave from As/Bs ; sync
// Thread t: act row = t>>2 (fixed -> z[8] in regs all loop), k-octet (t&3)*8.
// w1s K-slice held q-major [8][32] fp32: reads are 4x16B distinct, 16-way
// broadcast, conflict-free. Numerics identical to the unfused version.
// ---------------------------------------------------------------------------
__global__ __launch_bounds__(512) void k_fused(
    const float* __restrict__ x, const float* __restrict__ ry,
    const float* __restrict__ w1, const float* __restrict__ b1,
    const unsigned short* __restrict__ w2b, const float* __restrict__ b2,
    float* __restrict__ C) {
  __shared__ unsigned short As[128 * 32];  // 8 KB  [m][k] bf16
  __shared__ unsigned short Bs[256 * 32];  // 16 KB [n][k] bf16
  __shared__ float w1s[2][8][32];          // 2 KB  [buf][q][kidx] fp32
  __shared__ float b1s[2048];              // 8 KB

  const int t = threadIdx.x;
  const int lane = t & 63;
  const int w = t >> 6;
  const int mt = (int)(blockIdx.x >> 1);
  const int nt = (int)(blockIdx.x & 1);
  const int r0 = mt * 128;
  const int c0 = nt * 256;

  const int arow = t >> 2;      // 0..127: act row this thread produces
  const int k8 = (t & 3) * 8;   // k-octet within the 32-wide K-step

  // ---- prologue: z regs, b1 -> LDS, w1 slice 0 -> LDS ----
  float z[8];
  {
    const float* xr = x + (size_t)(r0 + arow) * 512;
    float4 x0 = *(const float4*)xr;
    float4 x1 = *(const float4*)(xr + 4);
    float4 ra = *(const float4*)ry;
    float4 rb = *(const float4*)(ry + 4);
    z[0] = __cosf(x0.x) * __cosf(ra.x);
    z[1] = __cosf(x0.y) * __cosf(ra.y);
    z[2] = __cosf(x0.z) * __cosf(ra.z);
    z[3] = __cosf(x0.w) * __cosf(ra.w);
    z[4] = __cosf(x1.x) * __cosf(rb.x);
    z[5] = __cosf(x1.y) * __cosf(rb.y);
    z[6] = __cosf(x1.z) * __cosf(rb.z);
    z[7] = __cosf(x1.w) * __cosf(rb.w);
  }
  {
    float4 v = *(const float4*)(b1 + t * 4);  // 512 thr x 16 B = all 8 KB
    *(float4*)&b1s[t * 4] = v;
  }
  if (t < 64) {  // w1 K-slice 0: 256 floats, transpose to q-major
    float4 v = *(const float4*)(w1 + t * 4);
    const int fl = t >> 1, q0 = (t & 1) * 4;
    w1s[0][q0 + 0][fl] = v.x;
    w1s[0][q0 + 1][fl] = v.y;
    w1s[0][q0 + 2][fl] = v.z;
    w1s[0][q0 + 3][fl] = v.w;
  }
  __syncthreads();

  // Bs staging: 1024 chunks of 16 B, thread t handles chunks t and t+512
  const unsigned short* gB1 =
      w2b + (size_t)(c0 + (t >> 2)) * 2048 + (t & 3) * 8;
  const unsigned short* gB2 = gB1 + (size_t)128 * 2048;
  char* lB1 = (char*)Bs + t * 16;
  char* lB2 = lB1 + 512 * 16;

  const int wm = (w >> 2) * 64;
  const int wn = (w & 3) * 64;
  const int fr = lane & 15;
  const int quad = lane >> 4;

  f32x4 acc[4][4];
#pragma unroll
  for (int i = 0; i < 4; ++i)
#pragma unroll
    for (int j = 0; j < 4; ++j) acc[i][j] = (f32x4){0.f, 0.f, 0.f, 0.f};

  const unsigned short* pAf = As + (wm + fr) * 32 + quad * 8;
  const unsigned short* pBf = Bs + (wn + fr) * 32 + quad * 8;
  unsigned short* pAw = As + arow * 32 + k8;

  for (int kt = 0; kt < 64; ++kt) {
    const int cur = kt & 1;

    // --- phase A: issue async Bs stage for kt; w1 prefetch for kt+1 ---
    async_copy16(gB1, lB1);
    async_copy16(gB2, lB2);
    gB1 += 32;
    gB2 += 32;
    float4 wpre;
    const bool do_w1 = (t < 64) && (kt < 63);  // wave-uniform branch
    if (do_w1) wpre = *(const float4*)(w1 + (kt + 1) * 256 + t * 4);

    // --- phase B: act compute (hides staging latency) ---
    float h[8];
    {
      float4 b0 = *(const float4*)&b1s[kt * 32 + k8];
      float4 b4 = *(const float4*)&b1s[kt * 32 + k8 + 4];
      h[0] = b0.x; h[1] = b0.y; h[2] = b0.z; h[3] = b0.w;
      h[4] = b4.x; h[5] = b4.y; h[6] = b4.z; h[7] = b4.w;
    }
#pragma unroll
    for (int q = 0; q < 8; ++q) {
      float4 wa = *(const float4*)&w1s[cur][q][k8];
      float4 wb = *(const float4*)&w1s[cur][q][k8 + 4];
      h[0] += z[q] * wa.x; h[1] += z[q] * wa.y;
      h[2] += z[q] * wa.z; h[3] += z[q] * wa.w;
      h[4] += z[q] * wb.x; h[5] += z[q] * wb.y;
      h[6] += z[q] * wb.z; h[7] += z[q] * wb.w;
    }
    unsigned short o[8];
#pragma unroll
    for (int j = 0; j < 8; ++j) o[j] = f2bf(fmaxf(h[j], 0.0f));
    uint4 pk;
    pk.x = o[0] | ((unsigned)o[1] << 16);
    pk.y = o[2] | ((unsigned)o[3] << 16);
    pk.z = o[4] | ((unsigned)o[5] << 16);
    pk.w = o[6] | ((unsigned)o[7] << 16);
    *(uint4*)pAw = pk;  // ds_write_b128, uniform bank load
    if (do_w1) {        // stage w1 slice kt+1 into the other buffer
      const int fl = t >> 1, q0 = (t & 1) * 4;
      const int nxt = cur ^ 1;
      w1s[nxt][q0 + 0][fl] = wpre.x;
      w1s[nxt][q0 + 1][fl] = wpre.y;
      w1s[nxt][q0 + 2][fl] = wpre.z;
      w1s[nxt][q0 + 3][fl] = wpre.w;
    }
    __syncthreads();  // As visible; Bs/w1s(kt+1) drained

    // --- phase C: MFMA ---
    s16x8 af[4], bfv[4];
#pragma unroll
    for (int i = 0; i < 4; ++i) af[i] = *(const s16x8*)(pAf + i * 16 * 32);
#pragma unroll
    for (int j = 0; j < 4; ++j) bfv[j] = *(const s16x8*)(pBf + j * 16 * 32);
#pragma unroll
    for (int i = 0; i < 4; ++i)
#pragma unroll
      for (int j = 0; j < 4; ++j)
        acc[i][j] = __builtin_amdgcn_mfma_f32_16x16x32_bf16(af[i], bfv[j],
                                                            acc[i][j], 0, 0, 0);
    __syncthreads();  // protect As/Bs from next iter's writes
  }

  // epilogue: C/D layout col = lane&15, row = quad*4 + reg (m89/m91 verified)
  float bias[4];
#pragma unroll
  for (int j = 0; j < 4; ++j) bias[j] = b2[c0 + wn + j * 16 + fr];
#pragma unroll
  for (int i = 0; i < 4; ++i) {
    const int rbase = r0 + wm + i * 16 + quad * 4;
#pragma unroll
    for (int rr = 0; rr < 4; ++rr) {
      float* crow = C + (size_t)(rbase + rr) * 512;
#pragma unroll
      for (int j = 0; j < 4; ++j)
        crow[c0 + wn + j * 16 + fr] = acc[i][j][rr] + bias[j];
    }
  }
}

// ---------------------------------------------------------------------------
// Emergency fallback (only if ws_size is tiny): fully fused fp32, 1 row/block.
// ---------------------------------------------------------------------------
__global__ __launch_bounds__(256) void k_naive(
    const float* __restrict__ x, const float* __restrict__ ry,
    const float* __restrict__ w1, const float* __restrict__ b1,
    const float* __restrict__ w2, const float* __restrict__ b2,
    float* __restrict__ out) {
  __shared__ float zsh[8];
  __shared__ float acts[2048];
  const int r = blockIdx.x;
  const int t = threadIdx.x;
  if (t < 8) zsh[t] = __cosf(x[(size_t)r * 512 + t]) * __cosf(ry[t]);
  __syncthreads();
  float z[8];
#pragma unroll
  for (int q = 0; q < 8; ++q) z[q] = zsh[q];
#pragma unroll
  for (int i = 0; i < 8; ++i) {
    const int f = t * 8 + i;
    const float* wr = w1 + (size_t)f * 8;
    float4 a = *(const float4*)wr;
    float4 b = *(const float4*)(wr + 4);
    float h = b1[f] + z[0] * a.x + z[1] * a.y + z[2] * a.z + z[3] * a.w +
              z[4] * b.x + z[5] * b.y + z[6] * b.z + z[7] * b.w;
    acts[f] = fmaxf(h, 0.0f);
  }
  __syncthreads();
  for (int ee = 0; ee < 2; ++ee) {
    const int e = t + ee * 256;
    const float* wr = w2 + (size_t)e * 2048;
    float acc = b2[e];
    for (int f = 0; f < 2048; f += 4) {
      float4 wv = *(const float4*)(wr + f);
      float4 av = *(const float4*)(acts + f);
      acc += av.x * wv.x + av.y * wv.y + av.z * wv.z + av.w * wv.w;
    }
    out[(size_t)r * 512 + e] = acc;
  }
}

extern "C" void kernel_launch(void* const* d_in, const int* in_sizes, int n_in,
                              void* d_out, int out_size, void* d_ws,
                              size_t ws_size, hipStream_t stream) {
  const float* x  = (const float*)d_in[0];
  const float* ry = (const float*)d_in[1];
  const float* w1 = (const float*)d_in[2];
  const float* b1 = (const float*)d_in[3];
  const float* w2 = (const float*)d_in[4];
  const float* b2 = (const float*)d_in[5];
  float* out = (float*)d_out;

  const size_t w2b_bytes = (size_t)512 * 2048 * 2;  // 2 MB bf16 w2
  if (ws_size < w2b_bytes) {
    k_naive<<<dim3(16384), dim3(256), 0, stream>>>(x, ry, w1, b1, w2, b2, out);
    return;
  }
  unsigned short* w2b = (unsigned short*)d_ws;
  k_w2<<<dim3(1024), dim3(256), 0, stream>>>(w2, w2b);
  k_fused<<<dim3(256), dim3(512), 0, stream>>>(x, ry, w1, b1, w2b, b2, out);
}